// Round 3
// baseline (195.548 us; speedup 1.0000x reference)
//
#include <hip/hip_runtime.h>
#include <math.h>

// Problem constants
#define N_  8
#define C_  256
#define G_  8
#define CG_ 32
#define K_  9
#define H_  64
#define W_  64
#define L_  (H_*W_)      // 4096
#define OM_ 216          // G*K*3
#define OMP_ 256         // padded om row stride (fp32), groups packed at g*27

using frag_ab = __attribute__((ext_vector_type(8))) short;   // 8 bf16
using frag_cd = __attribute__((ext_vector_type(4))) float;   // 4 fp32

__device__ __forceinline__ unsigned short f2bf(float f) {    // RNE fp32->bf16
    unsigned int u = __float_as_uint(f);
    u += 0x7FFFu + ((u >> 16) & 1u);
    return (unsigned short)(u >> 16);
}
__device__ __forceinline__ float bflo(unsigned int u) { return __uint_as_float(u << 16); }
__device__ __forceinline__ float bfhi(unsigned int u) { return __uint_as_float(u & 0xFFFF0000u); }

__device__ __forceinline__ void gld16(const void* g, void* l) {
    __builtin_amdgcn_global_load_lds((const __attribute__((address_space(1))) void*)g,
                                     (__attribute__((address_space(3))) void*)l, 16, 0, 0);
}

// bilinear tap -> (4 weights, 4 row-offsets<<9)
__device__ __forceinline__ void tapcalc(int l, int k, float offy, float offx, float mk,
                                        float4& wq, uint4& sq) {
    const int y = l >> 6, xp = l & 63;
    float py = (float)(y + k / 3 - 1) + offy;
    float px = (float)(xp + k % 3 - 1) + offx;
    float fy = floorf(py), fx = floorf(px);
    float ty = py - fy, tx = px - fx;
    int y0 = (int)fy, x0i = (int)fx;
    int y1 = y0 + 1, x1 = x0i + 1;
    float vy0 = ((unsigned)y0 < (unsigned)H_) ? 1.f : 0.f;
    float vy1 = ((unsigned)y1 < (unsigned)H_) ? 1.f : 0.f;
    float vx0 = ((unsigned)x0i < (unsigned)W_) ? 1.f : 0.f;
    float vx1 = ((unsigned)x1 < (unsigned)W_) ? 1.f : 0.f;
    int cy0 = min(max(y0, 0), H_ - 1), cy1 = min(max(y1, 0), H_ - 1);
    int cx0 = min(max(x0i, 0), W_ - 1), cx1 = min(max(x1, 0), W_ - 1);
    wq = make_float4(mk * (1.f - ty) * (1.f - tx) * vy0 * vx0,
                     mk * (1.f - ty) * tx         * vy0 * vx1,
                     mk * ty         * (1.f - tx) * vy1 * vx0,
                     mk * ty         * tx         * vy1 * vx1);
    sq = make_uint4((unsigned)((cy0 * W_ + cx0) << 9),
                    (unsigned)((cy0 * W_ + cx1) << 9),
                    (unsigned)((cy1 * W_ + cx0) << 9),
                    (unsigned)((cy1 * W_ + cx1) << 9));
}

// ---------------------------------------------------------------------------
// Fused prep: depthwise 3x3 conv + transpose + bf16 convert of BOTH the conv
// output (omb) and the raw x row (xb), single pass over x. ALSO converts the
// three weight matrices to bf16 (blocks with n==0).
// grid (C/32, H, N), block 256.  (unchanged from R2 - passing)
// ---------------------------------------------------------------------------
__global__ __launch_bounds__(256) void prep_kernel(const float* __restrict__ x,
                                                   const float* __restrict__ w,
                                                   const float* __restrict__ b,
                                                   const float* __restrict__ vp_w,
                                                   const float* __restrict__ om_w,
                                                   const float* __restrict__ om_b,
                                                   const float* __restrict__ op_w,
                                                   unsigned short* __restrict__ xb,
                                                   unsigned short* __restrict__ omb,
                                                   unsigned short* __restrict__ vp_wb,
                                                   unsigned short* __restrict__ om_wb,
                                                   float* __restrict__ om_bp,
                                                   unsigned short* __restrict__ op_wb) {
    const int n = blockIdx.z, y = blockIdx.y, c0 = blockIdx.x * 32;
    const int tid = threadIdx.x;
    __shared__ float xs[3][32][66];
    __shared__ __align__(16) unsigned short os[2][64][40];  // [0]=x bf16, [1]=conv
    if (tid < 192) {    // zero the x = -1 / 64 halo columns
        int r = tid / 64, c = (tid / 2) % 32, e = tid & 1;
        xs[r][c][e * 65] = 0.f;
    }
    const float* xbase = x + ((size_t)n * C_ + c0) * L_;
    for (int i = tid; i < 3 * 32 * 16; i += 256) {   // 3 rows x 32 ch x 16 float4
        int r = i >> 9, rem = i & 511, c = rem >> 4, x4 = (rem & 15) * 4;
        int yy = y + r - 1;
        float4 v = make_float4(0.f, 0.f, 0.f, 0.f);
        if ((unsigned)yy < (unsigned)H_) v = *(const float4*)(xbase + (size_t)c * L_ + yy * W_ + x4);
        xs[r][c][1 + x4] = v.x; xs[r][c][2 + x4] = v.y;
        xs[r][c][3 + x4] = v.z; xs[r][c][4 + x4] = v.w;
    }
    __syncthreads();

    const int c = tid & 31, x0 = (tid >> 5) * 8;
    float wv[9];
#pragma unroll
    for (int i = 0; i < 9; i++) wv[i] = w[(c0 + c) * 9 + i];
    const float bias = b[c0 + c];
    float o[8];
#pragma unroll
    for (int j = 0; j < 8; j++) o[j] = bias;
#pragma unroll
    for (int r = 0; r < 3; r++) {
        float v[10];
#pragma unroll
        for (int d = 0; d < 10; d++) v[d] = xs[r][c][x0 + d];
#pragma unroll
        for (int j = 0; j < 8; j++)
            o[j] += wv[r * 3] * v[j] + wv[r * 3 + 1] * v[j + 1] + wv[r * 3 + 2] * v[j + 2];
    }
#pragma unroll
    for (int j = 0; j < 8; j++) {
        os[0][x0 + j][c] = f2bf(xs[1][c][1 + x0 + j]);
        os[1][x0 + j][c] = f2bf(o[j]);
    }
    __syncthreads();

    const int l = tid >> 2, c8 = (tid & 3) * 8;
    uint4 va = *(const uint4*)&os[0][l][c8];
    uint4 vc = *(const uint4*)&os[1][l][c8];
    // channel-tiled: [n][kb][l][32]; wave store = contiguous 1 KB
    size_t dst = (((size_t)n * 8 + blockIdx.x) * L_ + y * W_ + l) * 32 + c8;
    *(uint4*)(xb + dst) = va;
    *(uint4*)(omb + dst) = vc;

    // Weight conversion, folded in: blocks with n==0 cover all indices.
    if (n == 0) {
        int idx = (blockIdx.x + 8 * blockIdx.y) * 256 + tid;   // 0..131071
        if (idx < C_ * C_) {
            vp_wb[idx] = f2bf(vp_w[idx]);
            op_wb[idx] = f2bf(op_w[idx]);
            om_wb[idx] = (idx < OM_ * C_) ? f2bf(om_w[idx]) : (unsigned short)0;
        }
        if (idx < OMP_) om_bp[idx] = (idx < OM_) ? om_b[idx] : 0.f;
    }
}

// ---------------------------------------------------------------------------
// Merged GEMM1+GEMM2 (blockIdx.z selects). Unchanged from R2 (passing).
// ---------------------------------------------------------------------------
__global__ __launch_bounds__(256) void gemm12_kernel(const unsigned short* __restrict__ xb,
                                                     const unsigned short* __restrict__ omb,
                                                     const unsigned short* __restrict__ vp_wb,
                                                     const unsigned short* __restrict__ om_wb,
                                                     const float* __restrict__ vp_b,
                                                     const float* __restrict__ om_bp,
                                                     unsigned short* __restrict__ valueb,
                                                     float* __restrict__ omf) {
    __shared__ unsigned short As[128 * 32];
    __shared__ unsigned short Bs[128 * 32];
    const int which = blockIdx.z;
    const unsigned short* A = which ? omb : xb;
    const unsigned short* B = which ? om_wb : vp_wb;
    const float* bias = which ? om_bp : vp_b;
    const int tid = threadIdx.x;
    const long i0 = (long)blockIdx.x * 128;
    const long j0 = (long)blockIdx.y * 128;
    const int nA = (int)(i0 >> 12);          // batch index (128-row blocks never straddle n)
    const int lofs = (int)(i0 & 4095);
    const unsigned short* Bb = B + j0 * C_;
    const int wave = tid >> 6, lane = tid & 63;
    const int iw = (wave & 1) * 64, jw = (wave >> 1) * 64;
    const int lm = lane & 15, kq = lane >> 4;
    const int srow = tid >> 2, scol = (tid & 3) * 8;

    frag_cd acc[4][4];
#pragma unroll
    for (int a = 0; a < 4; a++)
#pragma unroll
        for (int c = 0; c < 4; c++) acc[a][c] = (frag_cd){0.f, 0.f, 0.f, 0.f};

    for (int k0 = 0; k0 < C_; k0 += 32) {
        // A: channel-tiled -> fully contiguous stream for this K-step
        const unsigned short* ga0 = A + (((size_t)nA * 8 + (k0 >> 5)) * L_ + lofs + srow) * 32 + scol;
        const unsigned short* gb0 = Bb + (long)srow * C_ + k0 + scol;
        gld16(ga0,            As + tid * 8);
        gld16(ga0 + 64 * 32,  As + 2048 + tid * 8);
        gld16(gb0,            Bs + tid * 8);
        gld16(gb0 + 64 * C_,  Bs + 2048 + tid * 8);
        __syncthreads();
        frag_ab af[4], bfr[4];
#pragma unroll
        for (int mi = 0; mi < 4; mi++)
            af[mi] = *(const frag_ab*)&As[(iw + mi * 16 + lm) * 32 + kq * 8];
#pragma unroll
        for (int ni = 0; ni < 4; ni++)
            bfr[ni] = *(const frag_ab*)&Bs[(jw + ni * 16 + lm) * 32 + kq * 8];
#pragma unroll
        for (int mi = 0; mi < 4; mi++)
#pragma unroll
            for (int ni = 0; ni < 4; ni++)
                acc[mi][ni] = __builtin_amdgcn_mfma_f32_16x16x32_bf16(af[mi], bfr[ni], acc[mi][ni], 0, 0, 0);
        __syncthreads();
    }

    float bv[4];
#pragma unroll
    for (int ni = 0; ni < 4; ni++)
        bv[ni] = bias[(int)(j0 + jw + ni * 16 + lm)];

    const long ibase = i0 + iw + kq * 4;
    const long jbase = j0 + jw + lm;
#pragma unroll
    for (int mi = 0; mi < 4; mi++) {
#pragma unroll
        for (int ni = 0; ni < 4; ni++) {
            long j = jbase + ni * 16;
#pragma unroll
            for (int r = 0; r < 4; r++) {
                long i = ibase + mi * 16 + r;
                float v = acc[mi][ni][r] + bv[ni];
                if (which)
                    omf[i * OMP_ + j] = v;
                else
                    valueb[i * C_ + j] = f2bf(v);
            }
        }
    }
}

// ---------------------------------------------------------------------------
// Fused sampling + output projection, round 3: WAVE-PER-PIXEL gather.
// grid (N, L/64) [XCD-pinned: wgid%8 == n], block 512 (8 waves), LB(512,4).
//
// R2 diagnosis: per-block wall ~35 us of exposed latency (Occ 17.5%, all
// pipes <40%). Two causes: (a) 2 blocks/CU x 4 waves = 8 waves/CU, nothing
// hides the gather latency; (b) 4-thread/pair mapping makes each gather
// wave-instruction touch 16 scattered 64 B row segments.
//
// New mapping: wave = ONE pixel per rep; lanes = 8 g x 4 c8i x 2 corner
// halves. Each gather instruction now reads ONE fully-contiguous 512 B value
// row (all 256 ch), every byte used. 18 loads/thread/rep (was 36), halves
// reduced by one __shfl_xor(4). 8 waves/block -> 16 waves/CU.
// om tap params register-prefetched during previous rep's gather (T14).
// Phase C: 8 waves x (32q x 64px), same interm swizzle as R0 (proven).
// LDS 51.2 KB; out rows stay 256 B/block chunks (R1 lesson: ~256 B HBM
// write granularity).
// ---------------------------------------------------------------------------
__global__ __launch_bounds__(512, 4) void samplegemm_kernel(const unsigned short* __restrict__ value,
                                                            const float* __restrict__ om,
                                                            const unsigned short* __restrict__ opw,
                                                            float* __restrict__ out) {
    const int n = blockIdx.x, l0 = blockIdx.y * 64;
    const int tid = threadIdx.x;
    __shared__ __align__(16) unsigned short interm[64 * 256];   // 32 KB, swizzled
    __shared__ float4 wgt[64][9];                               // 9.2 KB
    __shared__ uint4  soff[64][9];                              // 9.2 KB

    const char* vbase = (const char*)(value + (size_t)n * L_ * C_);
    const int lp = tid >> 3;            // pair 0..63: pin = lp>>3 (pixel), g = lp&7
    const int g = lp & 7;
    const int pin = lp >> 3;
    const int sub = tid & 7;
    const int c8i = sub & 3;
    const int half = sub >> 2;          // corner half: 0 -> {00,01}, 1 -> {10,11}
    const int slot = g * 4 + c8i;       // channel-slot 0..31 (ch = slot*8)
    const char* vb = vbase + (size_t)(g * CG_ + c8i * 8) * 2;

    // tap items: 576 = 64 pairs x 9 taps; thread -> item tid (+ item 512+tid for tid<64)
    const int itA = tid, plA = itA / 9, kA = itA - plA * 9;
    const int itB = 512 + tid, plB = itB / 9, kB = itB - plB * 9;
    const float* omn = om + (size_t)n * L_ * OMP_;
    const float* soA0 = omn + (size_t)(l0 + (plA >> 3)) * OMP_ + (plA & 7) * 27;
    const float* soB0 = omn + (size_t)(l0 + (plB >> 3)) * OMP_ + (plB & 7) * 27;

    // prologue: prefetch rep 0 tap params into registers
    float aAy = soA0[2 * kA], aAx = soA0[2 * kA + 1], aAm = soA0[18 + kA];
    float aBy = 0.f, aBx = 0.f, aBm = 0.f;
    if (tid < 64) { aBy = soB0[2 * kB]; aBx = soB0[2 * kB + 1]; aBm = soB0[18 + kB]; }

    for (int rep = 0; rep < 8; rep++) {
        __syncthreads();   // wgt/soff safe to overwrite (prev chunk consumed)
        // --- tap compute from prefetched registers ---
        {
            float4 wq; uint4 sq;
            tapcalc(l0 + rep * 8 + (plA >> 3), kA, aAy, aAx, aAm, wq, sq);
            wgt[plA][kA] = wq; soff[plA][kA] = sq;
            if (tid < 64) {
                tapcalc(l0 + rep * 8 + (plB >> 3), kB, aBy, aBx, aBm, wq, sq);
                wgt[plB][kB] = wq; soff[plB][kB] = sq;
            }
        }
        __syncthreads();
        // --- T14: issue next rep's om loads; consumed after next barrier ---
        if (rep < 7) {
            const float* soA = soA0 + (size_t)(rep + 1) * 8 * OMP_;
            aAy = soA[2 * kA]; aAx = soA[2 * kA + 1]; aAm = soA[18 + kA];
            if (tid < 64) {
                const float* soB = soB0 + (size_t)(rep + 1) * 8 * OMP_;
                aBy = soB[2 * kB]; aBx = soB[2 * kB + 1]; aBm = soB[18 + kB];
            }
        }
        // --- gather: wave = one pixel; each lane 2 corners x 8 ch ---
        const int p = rep * 8 + pin;
        float acc[8] = {0.f, 0.f, 0.f, 0.f, 0.f, 0.f, 0.f, 0.f};
#pragma unroll
        for (int k = 0; k < K_; k++) {
            float4 wk = wgt[lp][k];
            uint4  ok = soff[lp][k];
            unsigned oA = half ? ok.z : ok.x; float wA = half ? wk.z : wk.x;
            unsigned oB = half ? ok.w : ok.y; float wB = half ? wk.w : wk.y;
            const uint4 vA = *(const uint4*)(vb + oA);
            const uint4 vB = *(const uint4*)(vb + oB);
#define ACC8(V, WW) { \
            acc[0] += WW * bflo(V.x); acc[1] += WW * bfhi(V.x); \
            acc[2] += WW * bflo(V.y); acc[3] += WW * bfhi(V.y); \
            acc[4] += WW * bflo(V.z); acc[5] += WW * bfhi(V.z); \
            acc[6] += WW * bflo(V.w); acc[7] += WW * bfhi(V.w); }
            ACC8(vA, wA) ACC8(vB, wB)
#undef ACC8
        }
        // reduce corner halves (lane ^ 4 = same pair/c8i, other half)
#pragma unroll
        for (int i = 0; i < 8; i++) acc[i] += __shfl_xor(acc[i], 4);
        if (half == 0) {
            uint4 pk;
            unsigned short* ps = (unsigned short*)&pk;
#pragma unroll
            for (int i = 0; i < 8; i++) ps[i] = f2bf(acc[i]);
            int phys = slot ^ (p & 7);
            *(uint4*)&interm[p * 256 + phys * 8] = pk;
        }
    }
    __syncthreads();

    // --- Phase C: 8 waves x (32q x 64px), 2x4 frags, K=256 in 8 steps ---
    const int wave = tid >> 6, lane = tid & 63;
    const int lm = lane & 15, kq = lane >> 4;
    const int q0w = wave * 32;
    frag_cd acc2[2][4];
#pragma unroll
    for (int a = 0; a < 2; a++)
#pragma unroll
        for (int c = 0; c < 4; c++) acc2[a][c] = (frag_cd){0.f, 0.f, 0.f, 0.f};

    for (int k0 = 0; k0 < C_; k0 += 32) {
        frag_ab af[2], bfr[4];
#pragma unroll
        for (int mi = 0; mi < 2; mi++)
            af[mi] = *(const frag_ab*)(opw + (size_t)(q0w + mi * 16 + lm) * C_ + k0 + kq * 8);
#pragma unroll
        for (int ni = 0; ni < 4; ni++) {
            int pxr = ni * 16 + lm;
            int phys = (k0 / 8 + kq) ^ (pxr & 7);
            bfr[ni] = *(const frag_ab*)&interm[pxr * 256 + phys * 8];
        }
#pragma unroll
        for (int mi = 0; mi < 2; mi++)
#pragma unroll
            for (int ni = 0; ni < 4; ni++)
                acc2[mi][ni] = __builtin_amdgcn_mfma_f32_16x16x32_bf16(af[mi], bfr[ni], acc2[mi][ni], 0, 0, 0);
    }

    float* ob = out + (size_t)n * C_ * L_ + l0;
#pragma unroll
    for (int mi = 0; mi < 2; mi++) {
#pragma unroll
        for (int ni = 0; ni < 4; ni++) {
            int pxr = ni * 16 + lm;
#pragma unroll
            for (int r = 0; r < 4; r++) {
                int q = q0w + mi * 16 + kq * 4 + r;
                ob[(size_t)q * L_ + pxr] = acc2[mi][ni][r];
            }
        }
    }
}

// ---------------------------------------------------------------------------
// Workspace layout (84,280,320 B total):
//   [0,        16777216)  xb  [n][kb][l][32] bf16 (channel-tiled)
//   [16777216, 33554432)  omb [n][kb][l][32] bf16 (channel-tiled)
//   [33554432, 50331648)  valueb (n,L,C) bf16
//   [50331648, 83886080)  omf (n,L,256) fp32 (full rows, pad cols zero)
//   [83886080, ...)       vp_wb, om_wb, op_wb bf16 (128KB each), om_bp fp32
// ---------------------------------------------------------------------------
extern "C" void kernel_launch(void* const* d_in, const int* in_sizes, int n_in,
                              void* d_out, int out_size, void* d_ws, size_t ws_size,
                              hipStream_t stream) {
    const float* x    = (const float*)d_in[0];
    const float* dw_w = (const float*)d_in[1];
    const float* dw_b = (const float*)d_in[2];
    const float* om_w = (const float*)d_in[3];
    const float* om_b = (const float*)d_in[4];
    const float* vp_w = (const float*)d_in[5];
    const float* vp_b = (const float*)d_in[6];
    const float* op_w = (const float*)d_in[7];
    float* out = (float*)d_out;

    char* ws = (char*)d_ws;
    unsigned short* xb      = (unsigned short*)(ws);
    unsigned short* omb     = (unsigned short*)(ws + 16777216);
    unsigned short* valueb  = (unsigned short*)(ws + 33554432);
    float*          omf     = (float*)(ws + 50331648);
    unsigned short* vp_wb   = (unsigned short*)(ws + 83886080);
    unsigned short* om_wb   = (unsigned short*)(ws + 84017152);
    unsigned short* op_wb   = (unsigned short*)(ws + 84148224);
    float*          om_bp   = (float*)(ws + 84279296);

    // 1) fused depthwise conv + x transpose + weight conversion
    prep_kernel<<<dim3(C_ / 32, H_, N_), 256, 0, stream>>>(
        x, dw_w, dw_b, vp_w, om_w, om_b, op_w,
        xb, omb, vp_wb, om_wb, om_bp, op_wb);
    // 2) value = xb @ vp_w^T + vp_b  AND  om = omb @ om_w^T + om_b
    gemm12_kernel<<<dim3(256, 2, 2), 256, 0, stream>>>(
        xb, omb, vp_wb, om_wb, vp_b, om_bp, valueb, omf);
    // 3) fused sampling + output projection -> out (NCHW fp32)
    //    grid (N, L/64): wgid%8 == n pins each batch's value slice to one XCD L2
    samplegemm_kernel<<<dim3(N_, L_ / 64), 512, 0, stream>>>(valueb, omf, op_wb, out);
}

// Round 4
// 174.128 us; speedup vs baseline: 1.1230x; 1.1230x over previous
//
#include <hip/hip_runtime.h>
#include <math.h>

// Problem constants
#define N_  8
#define C_  256
#define G_  8
#define CG_ 32
#define K_  9
#define H_  64
#define W_  64
#define L_  (H_*W_)      // 4096
#define OM_ 216          // G*K*3
#define OMP_ 256         // padded om row stride (fp32), groups packed at g*27

using frag_ab = __attribute__((ext_vector_type(8))) short;   // 8 bf16
using frag_cd = __attribute__((ext_vector_type(4))) float;   // 4 fp32

__device__ __forceinline__ unsigned short f2bf(float f) {    // RNE fp32->bf16
    unsigned int u = __float_as_uint(f);
    u += 0x7FFFu + ((u >> 16) & 1u);
    return (unsigned short)(u >> 16);
}
__device__ __forceinline__ float bflo(unsigned int u) { return __uint_as_float(u << 16); }
__device__ __forceinline__ float bfhi(unsigned int u) { return __uint_as_float(u & 0xFFFF0000u); }

__device__ __forceinline__ void gld16(const void* g, void* l) {
    __builtin_amdgcn_global_load_lds((const __attribute__((address_space(1))) void*)g,
                                     (__attribute__((address_space(3))) void*)l, 16, 0, 0);
}

// ---------------------------------------------------------------------------
// Fused prep: depthwise 3x3 conv + transpose + bf16 convert of BOTH the conv
// output (omb) and the raw x row (xb). R4: FOUR output rows per block (load
// 6 input rows once) -> x halo re-read drops from 3x to 1.5x (~200 -> ~100 MB
// issued reads; everything obeys the measured ~1.8 TB/s effective cap, so
// bytes ~= time). Weight conversion spread over the n==0 blocks (128 blocks
// x 2 chunks of 256).
// grid (C/32, H/4, N) = (8,16,8), block 256. LDS 60.9 KB -> 2 blocks/CU.
// ---------------------------------------------------------------------------
__global__ __launch_bounds__(256) void prep_kernel(const float* __restrict__ x,
                                                   const float* __restrict__ w,
                                                   const float* __restrict__ b,
                                                   const float* __restrict__ vp_w,
                                                   const float* __restrict__ om_w,
                                                   const float* __restrict__ om_b,
                                                   const float* __restrict__ op_w,
                                                   unsigned short* __restrict__ xb,
                                                   unsigned short* __restrict__ omb,
                                                   unsigned short* __restrict__ vp_wb,
                                                   unsigned short* __restrict__ om_wb,
                                                   float* __restrict__ om_bp,
                                                   unsigned short* __restrict__ op_wb) {
    const int n = blockIdx.z, y0 = blockIdx.y * 4, c0 = blockIdx.x * 32;
    const int tid = threadIdx.x;
    __shared__ float xs[6][32][66];                          // 50.7 KB
    __shared__ __align__(16) unsigned short os[2][64][40];   // 10.2 KB (per-row reuse)
    // zero the x = -1 / 64 halo columns for all 6 rows
    for (int i = tid; i < 384; i += 256) {
        int r = i / 64, c = (i / 2) % 32, e = i & 1;
        xs[r][c][e * 65] = 0.f;
    }
    const float* xbase = x + ((size_t)n * C_ + c0) * L_;
    for (int i = tid; i < 6 * 32 * 16; i += 256) {   // 6 rows x 32 ch x 16 float4
        int r = i >> 9, rem = i & 511, c = rem >> 4, x4 = (rem & 15) * 4;
        int yy = y0 + r - 1;
        float4 v = make_float4(0.f, 0.f, 0.f, 0.f);
        if ((unsigned)yy < (unsigned)H_) v = *(const float4*)(xbase + (size_t)c * L_ + yy * W_ + x4);
        xs[r][c][1 + x4] = v.x; xs[r][c][2 + x4] = v.y;
        xs[r][c][3 + x4] = v.z; xs[r][c][4 + x4] = v.w;
    }
    __syncthreads();

    const int c = tid & 31, x0 = (tid >> 5) * 8;
    float wv[9];
#pragma unroll
    for (int i = 0; i < 9; i++) wv[i] = w[(c0 + c) * 9 + i];
    const float bias = b[c0 + c];
    const int l = tid >> 2, c8 = (tid & 3) * 8;

    for (int rr = 0; rr < 4; rr++) {
        float o[8];
#pragma unroll
        for (int j = 0; j < 8; j++) o[j] = bias;
#pragma unroll
        for (int r = 0; r < 3; r++) {
            float v[10];
#pragma unroll
            for (int d = 0; d < 10; d++) v[d] = xs[rr + r][c][x0 + d];
#pragma unroll
            for (int j = 0; j < 8; j++)
                o[j] += wv[r * 3] * v[j] + wv[r * 3 + 1] * v[j + 1] + wv[r * 3 + 2] * v[j + 2];
        }
#pragma unroll
        for (int j = 0; j < 8; j++) {
            os[0][x0 + j][c] = f2bf(xs[rr + 1][c][1 + x0 + j]);
            os[1][x0 + j][c] = f2bf(o[j]);
        }
        __syncthreads();
        uint4 va = *(const uint4*)&os[0][l][c8];
        uint4 vc = *(const uint4*)&os[1][l][c8];
        // channel-tiled: [n][kb][l][32]; wave store = contiguous 1 KB
        size_t dst = (((size_t)n * 8 + blockIdx.x) * L_ + (y0 + rr) * W_ + l) * 32 + c8;
        *(uint4*)(xb + dst) = va;
        *(uint4*)(omb + dst) = vc;
        __syncthreads();   // os safe to overwrite next row
    }

    // Weight conversion: n==0 blocks = 8x16 = 128 blocks; 2 chunks each.
    if (n == 0) {
        int base = (blockIdx.x + 8 * blockIdx.y) * 256 + tid;   // 0..32767
#pragma unroll
        for (int rep2 = 0; rep2 < 2; rep2++) {
            int idx = base + rep2 * 32768;                       // 0..65535
            vp_wb[idx] = f2bf(vp_w[idx]);
            op_wb[idx] = f2bf(op_w[idx]);
            om_wb[idx] = (idx < OM_ * C_) ? f2bf(om_w[idx]) : (unsigned short)0;
        }
        if (base < OMP_) om_bp[base] = (base < OM_) ? om_b[base] : 0.f;
    }
}

// ---------------------------------------------------------------------------
// Merged GEMM1+GEMM2 (blockIdx.z selects). Unchanged from R2 (passing).
// ---------------------------------------------------------------------------
__global__ __launch_bounds__(256) void gemm12_kernel(const unsigned short* __restrict__ xb,
                                                     const unsigned short* __restrict__ omb,
                                                     const unsigned short* __restrict__ vp_wb,
                                                     const unsigned short* __restrict__ om_wb,
                                                     const float* __restrict__ vp_b,
                                                     const float* __restrict__ om_bp,
                                                     unsigned short* __restrict__ valueb,
                                                     float* __restrict__ omf) {
    __shared__ unsigned short As[128 * 32];
    __shared__ unsigned short Bs[128 * 32];
    const int which = blockIdx.z;
    const unsigned short* A = which ? omb : xb;
    const unsigned short* B = which ? om_wb : vp_wb;
    const float* bias = which ? om_bp : vp_b;
    const int tid = threadIdx.x;
    const long i0 = (long)blockIdx.x * 128;
    const long j0 = (long)blockIdx.y * 128;
    const int nA = (int)(i0 >> 12);          // batch index (128-row blocks never straddle n)
    const int lofs = (int)(i0 & 4095);
    const unsigned short* Bb = B + j0 * C_;
    const int wave = tid >> 6, lane = tid & 63;
    const int iw = (wave & 1) * 64, jw = (wave >> 1) * 64;
    const int lm = lane & 15, kq = lane >> 4;
    const int srow = tid >> 2, scol = (tid & 3) * 8;

    frag_cd acc[4][4];
#pragma unroll
    for (int a = 0; a < 4; a++)
#pragma unroll
        for (int c = 0; c < 4; c++) acc[a][c] = (frag_cd){0.f, 0.f, 0.f, 0.f};

    for (int k0 = 0; k0 < C_; k0 += 32) {
        // A: channel-tiled -> fully contiguous stream for this K-step
        const unsigned short* ga0 = A + (((size_t)nA * 8 + (k0 >> 5)) * L_ + lofs + srow) * 32 + scol;
        const unsigned short* gb0 = Bb + (long)srow * C_ + k0 + scol;
        gld16(ga0,            As + tid * 8);
        gld16(ga0 + 64 * 32,  As + 2048 + tid * 8);
        gld16(gb0,            Bs + tid * 8);
        gld16(gb0 + 64 * C_,  Bs + 2048 + tid * 8);
        __syncthreads();
        frag_ab af[4], bfr[4];
#pragma unroll
        for (int mi = 0; mi < 4; mi++)
            af[mi] = *(const frag_ab*)&As[(iw + mi * 16 + lm) * 32 + kq * 8];
#pragma unroll
        for (int ni = 0; ni < 4; ni++)
            bfr[ni] = *(const frag_ab*)&Bs[(jw + ni * 16 + lm) * 32 + kq * 8];
#pragma unroll
        for (int mi = 0; mi < 4; mi++)
#pragma unroll
            for (int ni = 0; ni < 4; ni++)
                acc[mi][ni] = __builtin_amdgcn_mfma_f32_16x16x32_bf16(af[mi], bfr[ni], acc[mi][ni], 0, 0, 0);
        __syncthreads();
    }

    float bv[4];
#pragma unroll
    for (int ni = 0; ni < 4; ni++)
        bv[ni] = bias[(int)(j0 + jw + ni * 16 + lm)];

    const long ibase = i0 + iw + kq * 4;
    const long jbase = j0 + jw + lm;
#pragma unroll
    for (int mi = 0; mi < 4; mi++) {
#pragma unroll
        for (int ni = 0; ni < 4; ni++) {
            long j = jbase + ni * 16;
#pragma unroll
            for (int r = 0; r < 4; r++) {
                long i = ibase + mi * 16 + r;
                float v = acc[mi][ni][r] + bv[ni];
                if (which)
                    omf[i * OMP_ + j] = v;
                else
                    valueb[i * C_ + j] = f2bf(v);
            }
        }
    }
}

// ---------------------------------------------------------------------------
// Fused sampling + output projection. R4 = R2 internals (proven 49.7 us,
// WRITE = logical 32.8 MB) + R3's XCD-pinned grid (N, L/64) (proven FETCH
// 55 -> 32.6 MB: each XCD's L2 holds only its batch's 2 MB value slice).
//
// Empirical law from R0/R2/R3: dur ~= hbm_bytes / 1.8 TB/s (scattered-access
// effective ceiling). So this round minimizes bytes: R2's write pattern
// (256 B chunks, no amplification) + R3's read locality.
// grid (N, L/64), block 256, LB(256,2).
// ---------------------------------------------------------------------------
__global__ __launch_bounds__(256, 2) void samplegemm_kernel(const unsigned short* __restrict__ value,
                                                            const float* __restrict__ om,
                                                            const unsigned short* __restrict__ opw,
                                                            float* __restrict__ out) {
    const int n = blockIdx.x, l0 = blockIdx.y * 64;
    const int tid = threadIdx.x;
    __shared__ __align__(16) unsigned short interm[64 * 256];   // 32 KB, swizzled
    __shared__ float4 wgt[64][9];                               // 9.2 KB
    __shared__ uint4  soff[64][9];                              // 9.2 KB

    const char* vbase = (const char*)(value + (size_t)n * L_ * C_);
    const int lp = tid >> 2;            // pair-within-chunk 0..63
    const int g = lp & 7;
    const int c8i = tid & 3;
    const int slot = tid & 31;          // = g*4 + c8i
    const char* vb = vbase + (size_t)(g * CG_ + c8i * 8) * 2;

    for (int rep = 0; rep < 8; rep++) {
        __syncthreads();   // wgt/soff safe to overwrite (prev chunk consumed)
        // --- tap precompute for this chunk's 64 pairs ---
        for (int it = tid; it < 576; it += 256) {
            int pl = it / 9, k = it - pl * 9;
            int p = rep * 8 + (pl >> 3), gg = pl & 7;
            int l = l0 + p, y = l >> 6, xp2 = l & 63;
            const float* so = om + ((size_t)n * L_ + l) * OMP_ + gg * 27;
            float offy = so[2 * k], offx = so[2 * k + 1], mk = so[18 + k];
            float py = (float)(y + k / 3 - 1) + offy;
            float px = (float)(xp2 + k % 3 - 1) + offx;
            float fy = floorf(py), fx = floorf(px);
            float ty = py - fy, tx = px - fx;
            int y0 = (int)fy, x0i = (int)fx;
            int y1 = y0 + 1, x1 = x0i + 1;
            float vy0 = ((unsigned)y0 < (unsigned)H_) ? 1.f : 0.f;
            float vy1 = ((unsigned)y1 < (unsigned)H_) ? 1.f : 0.f;
            float vx0 = ((unsigned)x0i < (unsigned)W_) ? 1.f : 0.f;
            float vx1 = ((unsigned)x1 < (unsigned)W_) ? 1.f : 0.f;
            int cy0 = min(max(y0, 0), H_ - 1), cy1 = min(max(y1, 0), H_ - 1);
            int cx0 = min(max(x0i, 0), W_ - 1), cx1 = min(max(x1, 0), W_ - 1);
            wgt[pl][k] = make_float4(mk * (1.f - ty) * (1.f - tx) * vy0 * vx0,
                                     mk * (1.f - ty) * tx         * vy0 * vx1,
                                     mk * ty         * (1.f - tx) * vy1 * vx0,
                                     mk * ty         * tx         * vy1 * vx1);
            soff[pl][k] = make_uint4((unsigned)((cy0 * W_ + cx0) << 9),
                                     (unsigned)((cy0 * W_ + cx1) << 9),
                                     (unsigned)((cy1 * W_ + cx0) << 9),
                                     (unsigned)((cy1 * W_ + cx1) << 9));
        }
        __syncthreads();
        // --- gather for this chunk ---
        const int p = rep * 8 + (lp >> 3);
        float acc[8] = {0.f, 0.f, 0.f, 0.f, 0.f, 0.f, 0.f, 0.f};
#pragma unroll
        for (int k = 0; k < K_; k++) {
            float4 wk = wgt[lp][k];
            uint4  ok = soff[lp][k];
            const uint4 v00 = *(const uint4*)(vb + ok.x);
            const uint4 v01 = *(const uint4*)(vb + ok.y);
            const uint4 v10 = *(const uint4*)(vb + ok.z);
            const uint4 v11 = *(const uint4*)(vb + ok.w);
#define ACC8(V, WW) { \
            acc[0] += WW * bflo(V.x); acc[1] += WW * bfhi(V.x); \
            acc[2] += WW * bflo(V.y); acc[3] += WW * bfhi(V.y); \
            acc[4] += WW * bflo(V.z); acc[5] += WW * bfhi(V.z); \
            acc[6] += WW * bflo(V.w); acc[7] += WW * bfhi(V.w); }
            ACC8(v00, wk.x) ACC8(v01, wk.y) ACC8(v10, wk.z) ACC8(v11, wk.w)
#undef ACC8
        }
        uint4 pk;
        unsigned short* ps = (unsigned short*)&pk;
#pragma unroll
        for (int i = 0; i < 8; i++) ps[i] = f2bf(acc[i]);
        int phys = slot ^ (p & 7);
        *(uint4*)&interm[p * 256 + phys * 8] = pk;
    }
    __syncthreads();

    // --- Phase C: per wave 64q x 64px, 4x4 frags, K=256 in 8 steps ---
    const int wave = tid >> 6, lane = tid & 63;
    const int lm = lane & 15, kq = lane >> 4;
    const int q0w = wave * 64;
    frag_cd acc2[4][4];
#pragma unroll
    for (int a = 0; a < 4; a++)
#pragma unroll
        for (int c = 0; c < 4; c++) acc2[a][c] = (frag_cd){0.f, 0.f, 0.f, 0.f};

    for (int k0 = 0; k0 < C_; k0 += 32) {
        frag_ab af[4], bfr[4];
#pragma unroll
        for (int mi = 0; mi < 4; mi++)
            af[mi] = *(const frag_ab*)(opw + (size_t)(q0w + mi * 16 + lm) * C_ + k0 + kq * 8);
#pragma unroll
        for (int ni = 0; ni < 4; ni++) {
            int pxr = ni * 16 + lm;
            int phys = (k0 / 8 + kq) ^ (pxr & 7);
            bfr[ni] = *(const frag_ab*)&interm[pxr * 256 + phys * 8];
        }
#pragma unroll
        for (int mi = 0; mi < 4; mi++)
#pragma unroll
            for (int ni = 0; ni < 4; ni++)
                acc2[mi][ni] = __builtin_amdgcn_mfma_f32_16x16x32_bf16(af[mi], bfr[ni], acc2[mi][ni], 0, 0, 0);
    }

    float* ob = out + (size_t)n * C_ * L_ + l0;
#pragma unroll
    for (int mi = 0; mi < 4; mi++) {
#pragma unroll
        for (int ni = 0; ni < 4; ni++) {
            int pxr = ni * 16 + lm;
#pragma unroll
            for (int r = 0; r < 4; r++) {
                int q = q0w + mi * 16 + kq * 4 + r;
                ob[(size_t)q * L_ + pxr] = acc2[mi][ni][r];
            }
        }
    }
}

// ---------------------------------------------------------------------------
// Workspace layout (84,280,320 B total):
//   [0,        16777216)  xb  [n][kb][l][32] bf16 (channel-tiled)
//   [16777216, 33554432)  omb [n][kb][l][32] bf16 (channel-tiled)
//   [33554432, 50331648)  valueb (n,L,C) bf16
//   [50331648, 83886080)  omf (n,L,256) fp32 (full rows, pad cols zero)
//   [83886080, ...)       vp_wb, om_wb, op_wb bf16 (128KB each), om_bp fp32
// ---------------------------------------------------------------------------
extern "C" void kernel_launch(void* const* d_in, const int* in_sizes, int n_in,
                              void* d_out, int out_size, void* d_ws, size_t ws_size,
                              hipStream_t stream) {
    const float* x    = (const float*)d_in[0];
    const float* dw_w = (const float*)d_in[1];
    const float* dw_b = (const float*)d_in[2];
    const float* om_w = (const float*)d_in[3];
    const float* om_b = (const float*)d_in[4];
    const float* vp_w = (const float*)d_in[5];
    const float* vp_b = (const float*)d_in[6];
    const float* op_w = (const float*)d_in[7];
    float* out = (float*)d_out;

    char* ws = (char*)d_ws;
    unsigned short* xb      = (unsigned short*)(ws);
    unsigned short* omb     = (unsigned short*)(ws + 16777216);
    unsigned short* valueb  = (unsigned short*)(ws + 33554432);
    float*          omf     = (float*)(ws + 50331648);
    unsigned short* vp_wb   = (unsigned short*)(ws + 83886080);
    unsigned short* om_wb   = (unsigned short*)(ws + 84017152);
    unsigned short* op_wb   = (unsigned short*)(ws + 84148224);
    float*          om_bp   = (float*)(ws + 84279296);

    // 1) fused depthwise conv + x transpose + weight conversion (4 rows/block)
    prep_kernel<<<dim3(C_ / 32, H_ / 4, N_), 256, 0, stream>>>(
        x, dw_w, dw_b, vp_w, om_w, om_b, op_w,
        xb, omb, vp_wb, om_wb, om_bp, op_wb);
    // 2) value = xb @ vp_w^T + vp_b  AND  om = omb @ om_w^T + om_b
    gemm12_kernel<<<dim3(256, 2, 2), 256, 0, stream>>>(
        xb, omb, vp_wb, om_wb, vp_b, om_bp, valueb, omf);
    // 3) fused sampling + output projection -> out (NCHW fp32)
    //    grid (N, L/64): wgid%8 == n pins each batch's value slice to one XCD L2
    samplegemm_kernel<<<dim3(N_, L_ / 64), 256, 0, stream>>>(valueb, omf, op_wb, out);
}

// Round 5
// 170.492 us; speedup vs baseline: 1.1470x; 1.0213x over previous
//
#include <hip/hip_runtime.h>
#include <math.h>

// Problem constants
#define N_  8
#define C_  256
#define G_  8
#define CG_ 32
#define K_  9
#define H_  64
#define W_  64
#define L_  (H_*W_)      // 4096
#define OM_ 216          // G*K*3
#define OMP_ 256         // padded om row stride (fp32), groups packed at g*27

using frag_ab = __attribute__((ext_vector_type(8))) short;   // 8 bf16
using frag_cd = __attribute__((ext_vector_type(4))) float;   // 4 fp32

__device__ __forceinline__ unsigned short f2bf(float f) {    // RNE fp32->bf16
    unsigned int u = __float_as_uint(f);
    u += 0x7FFFu + ((u >> 16) & 1u);
    return (unsigned short)(u >> 16);
}
__device__ __forceinline__ float bflo(unsigned int u) { return __uint_as_float(u << 16); }
__device__ __forceinline__ float bfhi(unsigned int u) { return __uint_as_float(u & 0xFFFF0000u); }

__device__ __forceinline__ void gld16(const void* g, void* l) {
    __builtin_amdgcn_global_load_lds((const __attribute__((address_space(1))) void*)g,
                                     (__attribute__((address_space(3))) void*)l, 16, 0, 0);
}

// bilinear tap -> (4 weights, 4 row-offsets<<9)
__device__ __forceinline__ void tapcalc(int l, int k, float offy, float offx, float mk,
                                        float4& wq, uint4& sq) {
    const int y = l >> 6, xp = l & 63;
    float py = (float)(y + k / 3 - 1) + offy;
    float px = (float)(xp + k % 3 - 1) + offx;
    float fy = floorf(py), fx = floorf(px);
    float ty = py - fy, tx = px - fx;
    int y0 = (int)fy, x0i = (int)fx;
    int y1 = y0 + 1, x1 = x0i + 1;
    float vy0 = ((unsigned)y0 < (unsigned)H_) ? 1.f : 0.f;
    float vy1 = ((unsigned)y1 < (unsigned)H_) ? 1.f : 0.f;
    float vx0 = ((unsigned)x0i < (unsigned)W_) ? 1.f : 0.f;
    float vx1 = ((unsigned)x1 < (unsigned)W_) ? 1.f : 0.f;
    int cy0 = min(max(y0, 0), H_ - 1), cy1 = min(max(y1, 0), H_ - 1);
    int cx0 = min(max(x0i, 0), W_ - 1), cx1 = min(max(x1, 0), W_ - 1);
    wq = make_float4(mk * (1.f - ty) * (1.f - tx) * vy0 * vx0,
                     mk * (1.f - ty) * tx         * vy0 * vx1,
                     mk * ty         * (1.f - tx) * vy1 * vx0,
                     mk * ty         * tx         * vy1 * vx1);
    sq = make_uint4((unsigned)((cy0 * W_ + cx0) << 9),
                    (unsigned)((cy0 * W_ + cx1) << 9),
                    (unsigned)((cy1 * W_ + cx0) << 9),
                    (unsigned)((cy1 * W_ + cx1) << 9));
}

// ---------------------------------------------------------------------------
// Fused prep: depthwise 3x3 conv + transpose + bf16 convert. 4 output rows
// per block (6 input rows loaded once -> 1.5x halo). Unchanged from R4.
// grid (C/32, H/4, N), block 256.
// ---------------------------------------------------------------------------
__global__ __launch_bounds__(256) void prep_kernel(const float* __restrict__ x,
                                                   const float* __restrict__ w,
                                                   const float* __restrict__ b,
                                                   const float* __restrict__ vp_w,
                                                   const float* __restrict__ om_w,
                                                   const float* __restrict__ om_b,
                                                   const float* __restrict__ op_w,
                                                   unsigned short* __restrict__ xb,
                                                   unsigned short* __restrict__ omb,
                                                   unsigned short* __restrict__ vp_wb,
                                                   unsigned short* __restrict__ om_wb,
                                                   float* __restrict__ om_bp,
                                                   unsigned short* __restrict__ op_wb) {
    const int n = blockIdx.z, y0 = blockIdx.y * 4, c0 = blockIdx.x * 32;
    const int tid = threadIdx.x;
    __shared__ float xs[6][32][66];                          // 50.7 KB
    __shared__ __align__(16) unsigned short os[2][64][40];   // 10.2 KB (per-row reuse)
    for (int i = tid; i < 384; i += 256) {
        int r = i / 64, c = (i / 2) % 32, e = i & 1;
        xs[r][c][e * 65] = 0.f;
    }
    const float* xbase = x + ((size_t)n * C_ + c0) * L_;
    for (int i = tid; i < 6 * 32 * 16; i += 256) {   // 6 rows x 32 ch x 16 float4
        int r = i >> 9, rem = i & 511, c = rem >> 4, x4 = (rem & 15) * 4;
        int yy = y0 + r - 1;
        float4 v = make_float4(0.f, 0.f, 0.f, 0.f);
        if ((unsigned)yy < (unsigned)H_) v = *(const float4*)(xbase + (size_t)c * L_ + yy * W_ + x4);
        xs[r][c][1 + x4] = v.x; xs[r][c][2 + x4] = v.y;
        xs[r][c][3 + x4] = v.z; xs[r][c][4 + x4] = v.w;
    }
    __syncthreads();

    const int c = tid & 31, x0 = (tid >> 5) * 8;
    float wv[9];
#pragma unroll
    for (int i = 0; i < 9; i++) wv[i] = w[(c0 + c) * 9 + i];
    const float bias = b[c0 + c];
    const int l = tid >> 2, c8 = (tid & 3) * 8;

    for (int rr = 0; rr < 4; rr++) {
        float o[8];
#pragma unroll
        for (int j = 0; j < 8; j++) o[j] = bias;
#pragma unroll
        for (int r = 0; r < 3; r++) {
            float v[10];
#pragma unroll
            for (int d = 0; d < 10; d++) v[d] = xs[rr + r][c][x0 + d];
#pragma unroll
            for (int j = 0; j < 8; j++)
                o[j] += wv[r * 3] * v[j] + wv[r * 3 + 1] * v[j + 1] + wv[r * 3 + 2] * v[j + 2];
        }
#pragma unroll
        for (int j = 0; j < 8; j++) {
            os[0][x0 + j][c] = f2bf(xs[rr + 1][c][1 + x0 + j]);
            os[1][x0 + j][c] = f2bf(o[j]);
        }
        __syncthreads();
        uint4 va = *(const uint4*)&os[0][l][c8];
        uint4 vc = *(const uint4*)&os[1][l][c8];
        // channel-tiled: [n][kb][l][32]; wave store = contiguous 1 KB
        size_t dst = (((size_t)n * 8 + blockIdx.x) * L_ + (y0 + rr) * W_ + l) * 32 + c8;
        *(uint4*)(xb + dst) = va;
        *(uint4*)(omb + dst) = vc;
        __syncthreads();   // os safe to overwrite next row
    }

    // Weight conversion: n==0 blocks = 8x16 = 128 blocks; 2 chunks each.
    if (n == 0) {
        int base = (blockIdx.x + 8 * blockIdx.y) * 256 + tid;   // 0..32767
#pragma unroll
        for (int rep2 = 0; rep2 < 2; rep2++) {
            int idx = base + rep2 * 32768;                       // 0..65535
            vp_wb[idx] = f2bf(vp_w[idx]);
            op_wb[idx] = f2bf(op_w[idx]);
            om_wb[idx] = (idx < OM_ * C_) ? f2bf(om_w[idx]) : (unsigned short)0;
        }
        if (base < OMP_) om_bp[base] = (base < OM_) ? om_b[base] : 0.f;
    }
}

// ---------------------------------------------------------------------------
// Merged GEMM1+GEMM2 (blockIdx.z selects). Unchanged from R2/R4 (passing).
// ---------------------------------------------------------------------------
__global__ __launch_bounds__(256) void gemm12_kernel(const unsigned short* __restrict__ xb,
                                                     const unsigned short* __restrict__ omb,
                                                     const unsigned short* __restrict__ vp_wb,
                                                     const unsigned short* __restrict__ om_wb,
                                                     const float* __restrict__ vp_b,
                                                     const float* __restrict__ om_bp,
                                                     unsigned short* __restrict__ valueb,
                                                     float* __restrict__ omf) {
    __shared__ unsigned short As[128 * 32];
    __shared__ unsigned short Bs[128 * 32];
    const int which = blockIdx.z;
    const unsigned short* A = which ? omb : xb;
    const unsigned short* B = which ? om_wb : vp_wb;
    const float* bias = which ? om_bp : vp_b;
    const int tid = threadIdx.x;
    const long i0 = (long)blockIdx.x * 128;
    const long j0 = (long)blockIdx.y * 128;
    const int nA = (int)(i0 >> 12);          // batch index (128-row blocks never straddle n)
    const int lofs = (int)(i0 & 4095);
    const unsigned short* Bb = B + j0 * C_;
    const int wave = tid >> 6, lane = tid & 63;
    const int iw = (wave & 1) * 64, jw = (wave >> 1) * 64;
    const int lm = lane & 15, kq = lane >> 4;
    const int srow = tid >> 2, scol = (tid & 3) * 8;

    frag_cd acc[4][4];
#pragma unroll
    for (int a = 0; a < 4; a++)
#pragma unroll
        for (int c = 0; c < 4; c++) acc[a][c] = (frag_cd){0.f, 0.f, 0.f, 0.f};

    for (int k0 = 0; k0 < C_; k0 += 32) {
        // A: channel-tiled -> fully contiguous stream for this K-step
        const unsigned short* ga0 = A + (((size_t)nA * 8 + (k0 >> 5)) * L_ + lofs + srow) * 32 + scol;
        const unsigned short* gb0 = Bb + (long)srow * C_ + k0 + scol;
        gld16(ga0,            As + tid * 8);
        gld16(ga0 + 64 * 32,  As + 2048 + tid * 8);
        gld16(gb0,            Bs + tid * 8);
        gld16(gb0 + 64 * C_,  Bs + 2048 + tid * 8);
        __syncthreads();
        frag_ab af[4], bfr[4];
#pragma unroll
        for (int mi = 0; mi < 4; mi++)
            af[mi] = *(const frag_ab*)&As[(iw + mi * 16 + lm) * 32 + kq * 8];
#pragma unroll
        for (int ni = 0; ni < 4; ni++)
            bfr[ni] = *(const frag_ab*)&Bs[(jw + ni * 16 + lm) * 32 + kq * 8];
#pragma unroll
        for (int mi = 0; mi < 4; mi++)
#pragma unroll
            for (int ni = 0; ni < 4; ni++)
                acc[mi][ni] = __builtin_amdgcn_mfma_f32_16x16x32_bf16(af[mi], bfr[ni], acc[mi][ni], 0, 0, 0);
        __syncthreads();
    }

    float bv[4];
#pragma unroll
    for (int ni = 0; ni < 4; ni++)
        bv[ni] = bias[(int)(j0 + jw + ni * 16 + lm)];

    const long ibase = i0 + iw + kq * 4;
    const long jbase = j0 + jw + lm;
#pragma unroll
    for (int mi = 0; mi < 4; mi++) {
#pragma unroll
        for (int ni = 0; ni < 4; ni++) {
            long j = jbase + ni * 16;
#pragma unroll
            for (int r = 0; r < 4; r++) {
                long i = ibase + mi * 16 + r;
                float v = acc[mi][ni][r] + bv[ni];
                if (which)
                    omf[i * OMP_ + j] = v;
                else
                    valueb[i * C_ + j] = f2bf(v);
            }
        }
    }
}

// ---------------------------------------------------------------------------
// Fused sampling + output projection, round 5: BARRIER-FREE rep loop.
//
// R4 evidence: dur invariant (48 us) under 2.4x FETCH reduction -> not
// BW-bound; floor = serialization (16 block barriers + 64-lane-divergent 4-B
// om reads + lockstep latency exposure). MfmaUtil 3.3 / VALUBusy 39 / Occ 17.
//
// Fix: the tap producer/consumer graph is wave-local (wave w's 16 pairs ==
// pixels {2w, 2w+1}). So per rep, each wave:
//   1. vmcnt(0): its om rows (issued LAST rep via global_load_lds) are in LDS
//   2. tap compute: reads ombuf (LDS), writes its wgt/soff table region.
//      All same-wave ds ops -> in-order, no barrier.
//   3. issues global_load_lds staging of NEXT rep's 2 om rows (coalesced
//      16-B segments; overlaps with this rep's gather)
//   4. gather 36 loads + 288 fma -> interm (wave-private rows)
// ZERO __syncthreads in the rep loop (was 16); one final barrier before
// phase C. Waves drift across reps and hide each other's latency.
// LDS 57.4 KB (interm 32 + tables 18.4 + ombuf 7) -> 2 blocks/CU.
// grid (N, L/64) XCD-pinned (R3/R4 proven: FETCH 55->23 MB). LB(256,2).
// ---------------------------------------------------------------------------
__global__ __launch_bounds__(256, 2) void samplegemm_kernel(const unsigned short* __restrict__ value,
                                                            const float* __restrict__ om,
                                                            const unsigned short* __restrict__ opw,
                                                            float* __restrict__ out) {
    const int n = blockIdx.x, l0 = blockIdx.y * 64;
    const int tid = threadIdx.x;
    __shared__ __align__(16) unsigned short interm[64 * 256];   // 32 KB, swizzled
    __shared__ __align__(16) float ombuf[8][224];               // 7 KB om-row stage
    __shared__ float4 wgt[64][9];                               // 9.2 KB
    __shared__ uint4  soff[64][9];                              // 9.2 KB

    const int wave = tid >> 6, lane = tid & 63;
    const int lp = tid >> 2;            // pair 0..63; wave w owns lp 16w..16w+15
    const int g = lp & 7;
    const int c8i = tid & 3;
    const int slot = tid & 31;          // = g*4 + c8i
    const char* vbase = (const char*)(value + (size_t)n * L_ * C_);
    const char* vb = vbase + (size_t)(g * CG_ + c8i * 8) * 2;

    const float* omn = om + (size_t)n * L_ * OMP_;
    // wave-private om staging: wave w stages pixel rows {2w, 2w+1} (224 floats
    // each = 56 f4; 112 segments = 2 gld16 issues, 2nd with 48 active lanes).
    float* obase = &ombuf[2 * wave][0];                 // wave-uniform dest base

    // precomputed per-lane source float4 indices for the two staging issues
    const int s0row = (lane < 56) ? 0 : 1;              // 0 -> p0, 1 -> p1
    const int s0idx = (lane < 56) ? lane : (lane - 56);

#define STAGE_OM(REP) { \
        const float* r0_ = omn + (size_t)(l0 + (REP) * 8 + 2 * wave) * OMP_; \
        gld16(r0_ + (size_t)s0row * OMP_ + s0idx * 4, obase); \
        if (lane < 48) gld16(r0_ + OMP_ + (8 + lane) * 4, (char*)obase + 1024); }

    STAGE_OM(0)

    for (int rep = 0; rep < 8; rep++) {
        // gld16 -> LDS dependency is untracked by the compiler: explicit drain.
        asm volatile("s_waitcnt vmcnt(0)" ::: "memory");
        // --- tap compute: 144 items (16 pairs x 9 taps) over 64 lanes ---
#pragma unroll
        for (int j = 0; j < 3; j++) {
            if (!(j == 2 && lane >= 16)) {
                int it = lane + j * 64;                  // 0..143
                int pl_loc = it / 9, k = it - pl_loc * 9;
                int pl = wave * 16 + pl_loc;
                int pic = pl >> 3;                       // pixel-in-chunk 0..7
                const float* ob2 = &ombuf[pic][(pl & 7) * 27];
                float offy = ob2[2 * k], offx = ob2[2 * k + 1], mk = ob2[18 + k];
                float4 wq; uint4 sq;
                tapcalc(l0 + rep * 8 + pic, k, offy, offx, mk, wq, sq);
                wgt[pl][k] = wq; soff[pl][k] = sq;
            }
        }
        // order: ombuf ds_reads above stay before the overwriting stage below
        asm volatile("" ::: "memory");
        if (rep < 7) STAGE_OM(rep + 1)
        asm volatile("" ::: "memory");
        // --- gather (table ds_writes -> ds_reads are same-wave, in-order) ---
        const int p = rep * 8 + (lp >> 3);
        float acc[8] = {0.f, 0.f, 0.f, 0.f, 0.f, 0.f, 0.f, 0.f};
#pragma unroll
        for (int k = 0; k < K_; k++) {
            float4 wk = wgt[lp][k];
            uint4  ok = soff[lp][k];
            const uint4 v00 = *(const uint4*)(vb + ok.x);
            const uint4 v01 = *(const uint4*)(vb + ok.y);
            const uint4 v10 = *(const uint4*)(vb + ok.z);
            const uint4 v11 = *(const uint4*)(vb + ok.w);
#define ACC8(V, WW) { \
            acc[0] += WW * bflo(V.x); acc[1] += WW * bfhi(V.x); \
            acc[2] += WW * bflo(V.y); acc[3] += WW * bfhi(V.y); \
            acc[4] += WW * bflo(V.z); acc[5] += WW * bfhi(V.z); \
            acc[6] += WW * bflo(V.w); acc[7] += WW * bfhi(V.w); }
            ACC8(v00, wk.x) ACC8(v01, wk.y) ACC8(v10, wk.z) ACC8(v11, wk.w)
#undef ACC8
        }
        uint4 pk;
        unsigned short* ps = (unsigned short*)&pk;
#pragma unroll
        for (int i = 0; i < 8; i++) ps[i] = f2bf(acc[i]);
        int phys = slot ^ (p & 7);
        *(uint4*)&interm[p * 256 + phys * 8] = pk;      // wave-private rows
    }
#undef STAGE_OM
    __syncthreads();   // the ONLY block barrier: interm ready for phase C

    // --- Phase C: per wave 64q x 64px, 4x4 frags, K=256 in 8 steps ---
    const int lm = lane & 15, kq = lane >> 4;
    const int q0w = wave * 64;
    frag_cd acc2[4][4];
#pragma unroll
    for (int a = 0; a < 4; a++)
#pragma unroll
        for (int c = 0; c < 4; c++) acc2[a][c] = (frag_cd){0.f, 0.f, 0.f, 0.f};

    for (int k0 = 0; k0 < C_; k0 += 32) {
        frag_ab af[4], bfr[4];
#pragma unroll
        for (int mi = 0; mi < 4; mi++)
            af[mi] = *(const frag_ab*)(opw + (size_t)(q0w + mi * 16 + lm) * C_ + k0 + kq * 8);
#pragma unroll
        for (int ni = 0; ni < 4; ni++) {
            int pxr = ni * 16 + lm;
            int phys = (k0 / 8 + kq) ^ (pxr & 7);
            bfr[ni] = *(const frag_ab*)&interm[pxr * 256 + phys * 8];
        }
#pragma unroll
        for (int mi = 0; mi < 4; mi++)
#pragma unroll
            for (int ni = 0; ni < 4; ni++)
                acc2[mi][ni] = __builtin_amdgcn_mfma_f32_16x16x32_bf16(af[mi], bfr[ni], acc2[mi][ni], 0, 0, 0);
    }

    float* ob = out + (size_t)n * C_ * L_ + l0;
#pragma unroll
    for (int mi = 0; mi < 4; mi++) {
#pragma unroll
        for (int ni = 0; ni < 4; ni++) {
            int pxr = ni * 16 + lm;
#pragma unroll
            for (int r = 0; r < 4; r++) {
                int q = q0w + mi * 16 + kq * 4 + r;
                ob[(size_t)q * L_ + pxr] = acc2[mi][ni][r];
            }
        }
    }
}

// ---------------------------------------------------------------------------
// Workspace layout (84,280,320 B total):
//   [0,        16777216)  xb  [n][kb][l][32] bf16 (channel-tiled)
//   [16777216, 33554432)  omb [n][kb][l][32] bf16 (channel-tiled)
//   [33554432, 50331648)  valueb (n,L,C) bf16
//   [50331648, 83886080)  omf (n,L,256) fp32 (full rows, pad cols zero)
//   [83886080, ...)       vp_wb, om_wb, op_wb bf16 (128KB each), om_bp fp32
// ---------------------------------------------------------------------------
extern "C" void kernel_launch(void* const* d_in, const int* in_sizes, int n_in,
                              void* d_out, int out_size, void* d_ws, size_t ws_size,
                              hipStream_t stream) {
    const float* x    = (const float*)d_in[0];
    const float* dw_w = (const float*)d_in[1];
    const float* dw_b = (const float*)d_in[2];
    const float* om_w = (const float*)d_in[3];
    const float* om_b = (const float*)d_in[4];
    const float* vp_w = (const float*)d_in[5];
    const float* vp_b = (const float*)d_in[6];
    const float* op_w = (const float*)d_in[7];
    float* out = (float*)d_out;

    char* ws = (char*)d_ws;
    unsigned short* xb      = (unsigned short*)(ws);
    unsigned short* omb     = (unsigned short*)(ws + 16777216);
    unsigned short* valueb  = (unsigned short*)(ws + 33554432);
    float*          omf     = (float*)(ws + 50331648);
    unsigned short* vp_wb   = (unsigned short*)(ws + 83886080);
    unsigned short* om_wb   = (unsigned short*)(ws + 84017152);
    unsigned short* op_wb   = (unsigned short*)(ws + 84148224);
    float*          om_bp   = (float*)(ws + 84279296);

    // 1) fused depthwise conv + x transpose + weight conversion (4 rows/block)
    prep_kernel<<<dim3(C_ / 32, H_ / 4, N_), 256, 0, stream>>>(
        x, dw_w, dw_b, vp_w, om_w, om_b, op_w,
        xb, omb, vp_wb, om_wb, om_bp, op_wb);
    // 2) value = xb @ vp_w^T + vp_b  AND  om = omb @ om_w^T + om_b
    gemm12_kernel<<<dim3(256, 2, 2), 256, 0, stream>>>(
        xb, omb, vp_wb, om_wb, vp_b, om_bp, valueb, omf);
    // 3) fused sampling + output projection -> out (NCHW fp32)
    //    grid (N, L/64): wgid%8 == n pins each batch's value slice to one XCD L2
    samplegemm_kernel<<<dim3(N_, L_ / 64), 256, 0, stream>>>(valueb, omf, op_wb, out);
}

// Round 6
// 166.763 us; speedup vs baseline: 1.1726x; 1.0224x over previous
//
#include <hip/hip_runtime.h>
#include <hip/hip_fp16.h>
#include <math.h>

// Problem constants
#define N_  8
#define C_  256
#define G_  8
#define CG_ 32
#define K_  9
#define H_  64
#define W_  64
#define L_  (H_*W_)      // 4096
#define OM_ 216          // G*K*3
#define OMP_ 256         // padded om row stride (fp32), groups packed at g*27

using frag_ab = __attribute__((ext_vector_type(8))) short;   // 8 bf16
using frag_cd = __attribute__((ext_vector_type(4))) float;   // 4 fp32

__device__ __forceinline__ unsigned short f2bf(float f) {    // RNE fp32->bf16
    unsigned int u = __float_as_uint(f);
    u += 0x7FFFu + ((u >> 16) & 1u);
    return (unsigned short)(u >> 16);
}
__device__ __forceinline__ unsigned short f2h(float f) {     // RNE fp32->fp16
    return __half_as_ushort(__float2half(f));
}

__device__ __forceinline__ void gld16(const void* g, void* l) {
    __builtin_amdgcn_global_load_lds((const __attribute__((address_space(1))) void*)g,
                                     (__attribute__((address_space(3))) void*)l, 16, 0, 0);
}

// bilinear tap -> (4 weights, 4 row-offsets<<9)
__device__ __forceinline__ void tapcalc(int l, int k, float offy, float offx, float mk,
                                        float4& wq, uint4& sq) {
    const int y = l >> 6, xp = l & 63;
    float py = (float)(y + k / 3 - 1) + offy;
    float px = (float)(xp + k % 3 - 1) + offx;
    float fy = floorf(py), fx = floorf(px);
    float ty = py - fy, tx = px - fx;
    int y0 = (int)fy, x0i = (int)fx;
    int y1 = y0 + 1, x1 = x0i + 1;
    float vy0 = ((unsigned)y0 < (unsigned)H_) ? 1.f : 0.f;
    float vy1 = ((unsigned)y1 < (unsigned)H_) ? 1.f : 0.f;
    float vx0 = ((unsigned)x0i < (unsigned)W_) ? 1.f : 0.f;
    float vx1 = ((unsigned)x1 < (unsigned)W_) ? 1.f : 0.f;
    int cy0 = min(max(y0, 0), H_ - 1), cy1 = min(max(y1, 0), H_ - 1);
    int cx0 = min(max(x0i, 0), W_ - 1), cx1 = min(max(x1, 0), W_ - 1);
    wq = make_float4(mk * (1.f - ty) * (1.f - tx) * vy0 * vx0,
                     mk * (1.f - ty) * tx         * vy0 * vx1,
                     mk * ty         * (1.f - tx) * vy1 * vx0,
                     mk * ty         * tx         * vy1 * vx1);
    sq = make_uint4((unsigned)((cy0 * W_ + cx0) << 9),
                    (unsigned)((cy0 * W_ + cx1) << 9),
                    (unsigned)((cy1 * W_ + cx0) << 9),
                    (unsigned)((cy1 * W_ + cx1) << 9));
}

// ---------------------------------------------------------------------------
// Fused prep: depthwise 3x3 conv + transpose + bf16 convert. 4 output rows
// per block (6 input rows loaded once -> 1.5x halo). Unchanged from R4/R5.
// grid (C/32, H/4, N), block 256.
// ---------------------------------------------------------------------------
__global__ __launch_bounds__(256) void prep_kernel(const float* __restrict__ x,
                                                   const float* __restrict__ w,
                                                   const float* __restrict__ b,
                                                   const float* __restrict__ vp_w,
                                                   const float* __restrict__ om_w,
                                                   const float* __restrict__ om_b,
                                                   const float* __restrict__ op_w,
                                                   unsigned short* __restrict__ xb,
                                                   unsigned short* __restrict__ omb,
                                                   unsigned short* __restrict__ vp_wb,
                                                   unsigned short* __restrict__ om_wb,
                                                   float* __restrict__ om_bp,
                                                   unsigned short* __restrict__ op_wb) {
    const int n = blockIdx.z, y0 = blockIdx.y * 4, c0 = blockIdx.x * 32;
    const int tid = threadIdx.x;
    __shared__ float xs[6][32][66];                          // 50.7 KB
    __shared__ __align__(16) unsigned short os[2][64][40];   // 10.2 KB (per-row reuse)
    for (int i = tid; i < 384; i += 256) {
        int r = i / 64, c = (i / 2) % 32, e = i & 1;
        xs[r][c][e * 65] = 0.f;
    }
    const float* xbase = x + ((size_t)n * C_ + c0) * L_;
    for (int i = tid; i < 6 * 32 * 16; i += 256) {   // 6 rows x 32 ch x 16 float4
        int r = i >> 9, rem = i & 511, c = rem >> 4, x4 = (rem & 15) * 4;
        int yy = y0 + r - 1;
        float4 v = make_float4(0.f, 0.f, 0.f, 0.f);
        if ((unsigned)yy < (unsigned)H_) v = *(const float4*)(xbase + (size_t)c * L_ + yy * W_ + x4);
        xs[r][c][1 + x4] = v.x; xs[r][c][2 + x4] = v.y;
        xs[r][c][3 + x4] = v.z; xs[r][c][4 + x4] = v.w;
    }
    __syncthreads();

    const int c = tid & 31, x0 = (tid >> 5) * 8;
    float wv[9];
#pragma unroll
    for (int i = 0; i < 9; i++) wv[i] = w[(c0 + c) * 9 + i];
    const float bias = b[c0 + c];
    const int l = tid >> 2, c8 = (tid & 3) * 8;

    for (int rr = 0; rr < 4; rr++) {
        float o[8];
#pragma unroll
        for (int j = 0; j < 8; j++) o[j] = bias;
#pragma unroll
        for (int r = 0; r < 3; r++) {
            float v[10];
#pragma unroll
            for (int d = 0; d < 10; d++) v[d] = xs[rr + r][c][x0 + d];
#pragma unroll
            for (int j = 0; j < 8; j++)
                o[j] += wv[r * 3] * v[j] + wv[r * 3 + 1] * v[j + 1] + wv[r * 3 + 2] * v[j + 2];
        }
#pragma unroll
        for (int j = 0; j < 8; j++) {
            os[0][x0 + j][c] = f2bf(xs[rr + 1][c][1 + x0 + j]);
            os[1][x0 + j][c] = f2bf(o[j]);
        }
        __syncthreads();
        uint4 va = *(const uint4*)&os[0][l][c8];
        uint4 vc = *(const uint4*)&os[1][l][c8];
        // channel-tiled: [n][kb][l][32]; wave store = contiguous 1 KB
        size_t dst = (((size_t)n * 8 + blockIdx.x) * L_ + (y0 + rr) * W_ + l) * 32 + c8;
        *(uint4*)(xb + dst) = va;
        *(uint4*)(omb + dst) = vc;
        __syncthreads();   // os safe to overwrite next row
    }

    // Weight conversion: n==0 blocks = 8x16 = 128 blocks; 2 chunks each.
    if (n == 0) {
        int base = (blockIdx.x + 8 * blockIdx.y) * 256 + tid;   // 0..32767
#pragma unroll
        for (int rep2 = 0; rep2 < 2; rep2++) {
            int idx = base + rep2 * 32768;                       // 0..65535
            vp_wb[idx] = f2bf(vp_w[idx]);
            op_wb[idx] = f2bf(op_w[idx]);
            om_wb[idx] = (idx < OM_ * C_) ? f2bf(om_w[idx]) : (unsigned short)0;
        }
        if (base < OMP_) om_bp[base] = (base < OM_) ? om_b[base] : 0.f;
    }
}

// ---------------------------------------------------------------------------
// Merged GEMM1+GEMM2 (blockIdx.z selects). R6: FULL-N tiles 128x256 so each
// A row is staged ONCE (was twice with j0 in {0,128}) -> -33.5 MB A fetch,
// half the blocks. acc 4x8 frags (128 VGPR), LB(256,2) keeps 8 waves/CU.
// z=0 output valueb is now FP16 (f2h) for samplegemm's v_fma_mix gather.
// grid (256, 1, 2), block 256 (4 waves), BK=32, mfma 16x16x32.
// ---------------------------------------------------------------------------
__global__ __launch_bounds__(256, 2) void gemm12_kernel(const unsigned short* __restrict__ xb,
                                                        const unsigned short* __restrict__ omb,
                                                        const unsigned short* __restrict__ vp_wb,
                                                        const unsigned short* __restrict__ om_wb,
                                                        const float* __restrict__ vp_b,
                                                        const float* __restrict__ om_bp,
                                                        unsigned short* __restrict__ valueb,
                                                        float* __restrict__ omf) {
    __shared__ unsigned short As[128 * 32];
    __shared__ unsigned short Bs[256 * 32];
    const int which = blockIdx.z;
    const unsigned short* A = which ? omb : xb;
    const unsigned short* B = which ? om_wb : vp_wb;
    const float* bias = which ? om_bp : vp_b;
    const int tid = threadIdx.x;
    const long i0 = (long)blockIdx.x * 128;
    const int nA = (int)(i0 >> 12);          // batch index (128-row blocks never straddle n)
    const int lofs = (int)(i0 & 4095);
    const int wave = tid >> 6, lane = tid & 63;
    const int iw = (wave & 1) * 64, jw = (wave >> 1) * 128;
    const int lm = lane & 15, kq = lane >> 4;
    const int srow = tid >> 2, scol = (tid & 3) * 8;

    frag_cd acc[4][8];
#pragma unroll
    for (int a = 0; a < 4; a++)
#pragma unroll
        for (int c = 0; c < 8; c++) acc[a][c] = (frag_cd){0.f, 0.f, 0.f, 0.f};

    for (int k0 = 0; k0 < C_; k0 += 32) {
        // A: channel-tiled -> fully contiguous stream for this K-step
        const unsigned short* ga0 = A + (((size_t)nA * 8 + (k0 >> 5)) * L_ + lofs + srow) * 32 + scol;
        const unsigned short* gb0 = B + (long)srow * C_ + k0 + scol;
        gld16(ga0,             As + tid * 8);
        gld16(ga0 + 64 * 32,   As + 2048 + tid * 8);
        gld16(gb0,             Bs + tid * 8);
        gld16(gb0 + 64 * C_,   Bs + 2048 + tid * 8);
        gld16(gb0 + 128 * C_,  Bs + 4096 + tid * 8);
        gld16(gb0 + 192 * C_,  Bs + 6144 + tid * 8);
        __syncthreads();
        frag_ab af[4], bfr[8];
#pragma unroll
        for (int mi = 0; mi < 4; mi++)
            af[mi] = *(const frag_ab*)&As[(iw + mi * 16 + lm) * 32 + kq * 8];
#pragma unroll
        for (int ni = 0; ni < 8; ni++)
            bfr[ni] = *(const frag_ab*)&Bs[(jw + ni * 16 + lm) * 32 + kq * 8];
#pragma unroll
        for (int mi = 0; mi < 4; mi++)
#pragma unroll
            for (int ni = 0; ni < 8; ni++)
                acc[mi][ni] = __builtin_amdgcn_mfma_f32_16x16x32_bf16(af[mi], bfr[ni], acc[mi][ni], 0, 0, 0);
        __syncthreads();
    }

    float bv[8];
#pragma unroll
    for (int ni = 0; ni < 8; ni++)
        bv[ni] = bias[jw + ni * 16 + lm];

    const long ibase = i0 + iw + kq * 4;
    const int jbase = jw + lm;
#pragma unroll
    for (int mi = 0; mi < 4; mi++) {
#pragma unroll
        for (int ni = 0; ni < 8; ni++) {
            int jj = jbase + ni * 16;
#pragma unroll
            for (int r = 0; r < 4; r++) {
                long i = ibase + mi * 16 + r;
                float v = acc[mi][ni][r] + bv[ni];
                if (which)
                    omf[i * OMP_ + jj] = v;
                else
                    valueb[i * C_ + jj] = f2h(v);   // FP16 value (fma_mix gather)
            }
        }
    }
}

// ---------------------------------------------------------------------------
// Fused sampling + output projection, round 6: FP16 value + v_fma_mix gather.
//
// R5 result: barrier-free rep loop 48->45 us; falsifier fired (VALUBusy 41%,
// floor persists) -> per-wave issue + dependency cost dominates. Gather ACC
// was 2 VALU/element (bf16 unpack + fma). With valueb in FP16, clang emits
// v_fma_mix_f32 (fp16 operand consumed inside the FMA, op_sel half-select):
// 1 VALU/element -> gather VALU halves (~9 us of the 18.5 us VALU issue).
// fp16 mantissa (11b) > bf16 (8b), values O(1) -> precision improves.
// Everything else unchanged from R5 (proven): barrier-free wave-local rep
// loop, om staged via global_load_lds, XCD-pinned grid (N, L/64), interm
// bf16 + swizzle, phase C MFMA, 256 B out chunks. LDS 57.4 KB, LB(256,2).
// ---------------------------------------------------------------------------
__global__ __launch_bounds__(256, 2) void samplegemm_kernel(const unsigned short* __restrict__ value,
                                                            const float* __restrict__ om,
                                                            const unsigned short* __restrict__ opw,
                                                            float* __restrict__ out) {
    const int n = blockIdx.x, l0 = blockIdx.y * 64;
    const int tid = threadIdx.x;
    __shared__ __align__(16) unsigned short interm[64 * 256];   // 32 KB, swizzled
    __shared__ __align__(16) float ombuf[8][224];               // 7 KB om-row stage
    __shared__ float4 wgt[64][9];                               // 9.2 KB
    __shared__ uint4  soff[64][9];                              // 9.2 KB

    const int wave = tid >> 6, lane = tid & 63;
    const int lp = tid >> 2;            // pair 0..63; wave w owns lp 16w..16w+15
    const int g = lp & 7;
    const int c8i = tid & 3;
    const int slot = tid & 31;          // = g*4 + c8i
    const char* vbase = (const char*)(value + (size_t)n * L_ * C_);
    const char* vb = vbase + (size_t)(g * CG_ + c8i * 8) * 2;

    const float* omn = om + (size_t)n * L_ * OMP_;
    // wave-private om staging: wave w stages pixel rows {2w, 2w+1} (224 floats
    // each = 56 f4; 112 segments = 2 gld16 issues, 2nd with 48 active lanes).
    float* obase = &ombuf[2 * wave][0];                 // wave-uniform dest base

    const int s0row = (lane < 56) ? 0 : 1;              // 0 -> p0, 1 -> p1
    const int s0idx = (lane < 56) ? lane : (lane - 56);

#define STAGE_OM(REP) { \
        const float* r0_ = omn + (size_t)(l0 + (REP) * 8 + 2 * wave) * OMP_; \
        gld16(r0_ + (size_t)s0row * OMP_ + s0idx * 4, obase); \
        if (lane < 48) gld16(r0_ + OMP_ + (8 + lane) * 4, (char*)obase + 1024); }

    STAGE_OM(0)

    for (int rep = 0; rep < 8; rep++) {
        // gld16 -> LDS dependency is untracked by the compiler: explicit drain.
        asm volatile("s_waitcnt vmcnt(0)" ::: "memory");
        // --- tap compute: 144 items (16 pairs x 9 taps) over 64 lanes ---
#pragma unroll
        for (int j = 0; j < 3; j++) {
            if (!(j == 2 && lane >= 16)) {
                int it = lane + j * 64;                  // 0..143
                int pl_loc = it / 9, k = it - pl_loc * 9;
                int pl = wave * 16 + pl_loc;
                int pic = pl >> 3;                       // pixel-in-chunk 0..7
                const float* ob2 = &ombuf[pic][(pl & 7) * 27];
                float offy = ob2[2 * k], offx = ob2[2 * k + 1], mk = ob2[18 + k];
                float4 wq; uint4 sq;
                tapcalc(l0 + rep * 8 + pic, k, offy, offx, mk, wq, sq);
                wgt[pl][k] = wq; soff[pl][k] = sq;
            }
        }
        // order: ombuf ds_reads above stay before the overwriting stage below
        asm volatile("" ::: "memory");
        if (rep < 7) STAGE_OM(rep + 1)
        asm volatile("" ::: "memory");
        // --- gather (table ds_writes -> ds_reads are same-wave, in-order) ---
        const int p = rep * 8 + (lp >> 3);
        float acc[8] = {0.f, 0.f, 0.f, 0.f, 0.f, 0.f, 0.f, 0.f};
#pragma unroll
        for (int k = 0; k < K_; k++) {
            float4 wk = wgt[lp][k];
            uint4  ok = soff[lp][k];
            const uint4 v00 = *(const uint4*)(vb + ok.x);
            const uint4 v01 = *(const uint4*)(vb + ok.y);
            const uint4 v10 = *(const uint4*)(vb + ok.z);
            const uint4 v11 = *(const uint4*)(vb + ok.w);
            // fp16 value: 1 VALU/elem via v_fma_mix_f32 (fpext fused into fma)
#define ACC8(V, WW) { \
            const __half2* h_ = (const __half2*)&V; \
            acc[0] += WW * __half2float(h_[0].x); acc[1] += WW * __half2float(h_[0].y); \
            acc[2] += WW * __half2float(h_[1].x); acc[3] += WW * __half2float(h_[1].y); \
            acc[4] += WW * __half2float(h_[2].x); acc[5] += WW * __half2float(h_[2].y); \
            acc[6] += WW * __half2float(h_[3].x); acc[7] += WW * __half2float(h_[3].y); }
            ACC8(v00, wk.x) ACC8(v01, wk.y) ACC8(v10, wk.z) ACC8(v11, wk.w)
#undef ACC8
        }
        uint4 pk;
        unsigned short* ps = (unsigned short*)&pk;
#pragma unroll
        for (int i = 0; i < 8; i++) ps[i] = f2bf(acc[i]);
        int phys = slot ^ (p & 7);
        *(uint4*)&interm[p * 256 + phys * 8] = pk;      // wave-private rows
    }
#undef STAGE_OM
    __syncthreads();   // the ONLY block barrier: interm ready for phase C

    // --- Phase C: per wave 64q x 64px, 4x4 frags, K=256 in 8 steps ---
    const int lm = lane & 15, kq = lane >> 4;
    const int q0w = wave * 64;
    frag_cd acc2[4][4];
#pragma unroll
    for (int a = 0; a < 4; a++)
#pragma unroll
        for (int c = 0; c < 4; c++) acc2[a][c] = (frag_cd){0.f, 0.f, 0.f, 0.f};

    for (int k0 = 0; k0 < C_; k0 += 32) {
        frag_ab af[4], bfr[4];
#pragma unroll
        for (int mi = 0; mi < 4; mi++)
            af[mi] = *(const frag_ab*)(opw + (size_t)(q0w + mi * 16 + lm) * C_ + k0 + kq * 8);
#pragma unroll
        for (int ni = 0; ni < 4; ni++) {
            int pxr = ni * 16 + lm;
            int phys = (k0 / 8 + kq) ^ (pxr & 7);
            bfr[ni] = *(const frag_ab*)&interm[pxr * 256 + phys * 8];
        }
#pragma unroll
        for (int mi = 0; mi < 4; mi++)
#pragma unroll
            for (int ni = 0; ni < 4; ni++)
                acc2[mi][ni] = __builtin_amdgcn_mfma_f32_16x16x32_bf16(af[mi], bfr[ni], acc2[mi][ni], 0, 0, 0);
    }

    float* ob = out + (size_t)n * C_ * L_ + l0;
#pragma unroll
    for (int mi = 0; mi < 4; mi++) {
#pragma unroll
        for (int ni = 0; ni < 4; ni++) {
            int pxr = ni * 16 + lm;
#pragma unroll
            for (int r = 0; r < 4; r++) {
                int q = q0w + mi * 16 + kq * 4 + r;
                ob[(size_t)q * L_ + pxr] = acc2[mi][ni][r];
            }
        }
    }
}

// ---------------------------------------------------------------------------
// Workspace layout (84,280,320 B total):
//   [0,        16777216)  xb  [n][kb][l][32] bf16 (channel-tiled)
//   [16777216, 33554432)  omb [n][kb][l][32] bf16 (channel-tiled)
//   [33554432, 50331648)  valueb (n,L,C) FP16
//   [50331648, 83886080)  omf (n,L,256) fp32 (full rows, pad cols zero)
//   [83886080, ...)       vp_wb, om_wb, op_wb bf16 (128KB each), om_bp fp32
// ---------------------------------------------------------------------------
extern "C" void kernel_launch(void* const* d_in, const int* in_sizes, int n_in,
                              void* d_out, int out_size, void* d_ws, size_t ws_size,
                              hipStream_t stream) {
    const float* x    = (const float*)d_in[0];
    const float* dw_w = (const float*)d_in[1];
    const float* dw_b = (const float*)d_in[2];
    const float* om_w = (const float*)d_in[3];
    const float* om_b = (const float*)d_in[4];
    const float* vp_w = (const float*)d_in[5];
    const float* vp_b = (const float*)d_in[6];
    const float* op_w = (const float*)d_in[7];
    float* out = (float*)d_out;

    char* ws = (char*)d_ws;
    unsigned short* xb      = (unsigned short*)(ws);
    unsigned short* omb     = (unsigned short*)(ws + 16777216);
    unsigned short* valueb  = (unsigned short*)(ws + 33554432);
    float*          omf     = (float*)(ws + 50331648);
    unsigned short* vp_wb   = (unsigned short*)(ws + 83886080);
    unsigned short* om_wb   = (unsigned short*)(ws + 84017152);
    unsigned short* op_wb   = (unsigned short*)(ws + 84148224);
    float*          om_bp   = (float*)(ws + 84279296);

    // 1) fused depthwise conv + x transpose + weight conversion (4 rows/block)
    prep_kernel<<<dim3(C_ / 32, H_ / 4, N_), 256, 0, stream>>>(
        x, dw_w, dw_b, vp_w, om_w, om_b, op_w,
        xb, omb, vp_wb, om_wb, om_bp, op_wb);
    // 2) value = xb @ vp_w^T + vp_b (fp16)  AND  om = omb @ om_w^T + om_b
    //    full-N 128x256 tiles: each A row staged once
    gemm12_kernel<<<dim3(256, 1, 2), 256, 0, stream>>>(
        xb, omb, vp_wb, om_wb, vp_b, om_bp, valueb, omf);
    // 3) fused sampling + output projection -> out (NCHW fp32)
    //    grid (N, L/64): wgid%8 == n pins each batch's value slice to one XCD L2
    samplegemm_kernel<<<dim3(N_, L_ / 64), 256, 0, stream>>>(valueb, omf, op_wb, out);
}